// Round 11
// baseline (481.608 us; speedup 1.0000x reference)
//
#include <hip/hip_runtime.h>

// Problem constants (from reference setup_inputs)
constexpr int B = 16;
constexpr int D = 256;
constexpr int K = 18;
constexpr int KH = 9;           // half-K (lane-pair split)
constexpr int SZ = 128;
constexpr int S = SZ * SZ;      // 16384 positions per plane
constexpr int N = S / 2;        // 8192 sampled positions
constexpr int PB = 512;         // positions per block

// ---------------------------------------------------------------------------
// Prep (identical to passing rounds 5-10): blocks 0..31 scatter mask ones
// (mask pre-zeroed by memset); blocks 32..103 compute p2 = ||proto||^2 fp64.
// ---------------------------------------------------------------------------
__global__ __launch_bounds__(256) void prep2_kernel(
    const float* __restrict__ proto,
    const int* __restrict__ idx,
    unsigned char* __restrict__ mask,
    double* __restrict__ p2) {
  const int blk = blockIdx.x;
  if (blk < 32) {
    mask[idx[blk * 256 + threadIdx.x]] = 1;   // indices are a permutation
  } else {
    const int row  = (blk - 32) * 4 + (threadIdx.x >> 6);  // 0..287 = b*K+k
    const int lane = threadIdx.x & 63;
    const float4 v = *(const float4*)(proto + (size_t)row * D + lane * 4);
    double s = (double)v.x * (double)v.x + (double)v.y * (double)v.y
             + (double)v.z * (double)v.z + (double)v.w * (double)v.w;
#pragma unroll
    for (int off = 1; off < 64; off <<= 1)
      s += __shfl_xor(s, off, 64);
    if (lane == 0) p2[row] = s;
  }
}

// Per-d-group dot-product step: 8 planes, 4 positions, my 9-k half.
#define COMPUTE_GROUP(FV, DBASE)                                   \
  {                                                                \
    _Pragma("unroll")                                              \
    for (int jd = 0; jd < 8; ++jd) {                               \
      const double f0 = (double)FV[jd].x;                          \
      const double f1 = (double)FV[jd].y;                          \
      const double f2 = (double)FV[jd].z;                          \
      const double f3 = (double)FV[jd].w;                          \
      const double* pr = &spd[(DBASE) + jd][kh * KH];              \
      _Pragma("unroll")                                            \
      for (int j = 0; j < KH; ++j) {                               \
        const double pk = pr[j];                                   \
        acc[0][j] += f0 * pk;                                      \
        acc[1][j] += f1 * pk;                                      \
        acc[2][j] += f2 * pk;                                      \
        acc[3][j] += f3 * pk;                                      \
      }                                                            \
    }                                                              \
  }

// ---------------------------------------------------------------------------
// Fused argmin + output. Block = 256 threads (4 waves), (b, 512-pos chunk).
// vs round 10 (structure identical, absmax 0.0) two changes:
//  1. d-ROTATION: block walks d-groups in cyclic order starting at
//     rot=(chunk+4b)&31. All 512 co-resident blocks previously read the
//     same 64KB-strided address class in lockstep (identical low-16 addr
//     bits) -> HBM channel hotspot, the measured 2.5-3.3 TB/s wall (r3/r5/
//     r10) vs 7.2 TB/s for sequential reads (r5 scatter). Rotation spreads
//     blocks uniformly over the 32 address classes at any instant.
//     fp64 accumulation in rotated-but-fixed order: same assoc-change class
//     as r1's d-split (absmax 0.0).
//  2. PREFETCH: ping-pong fvA/fvB (static names, no runtime indexing) --
//     next group's 8 loads issued before computing current group, hiding
//     ~700cy latency under ~600cy of fp64 FMAs.
// ---------------------------------------------------------------------------
__global__ __launch_bounds__(256, 2) void fused_kernel(
    const float* __restrict__ assp,
    const float* __restrict__ proto,
    const double* __restrict__ p2,
    const unsigned char* __restrict__ mask,
    float* __restrict__ out) {
  __shared__ double spd[D][K];          // 36 KiB, dot phase
  __shared__ float  spf[D][K];          // 18 KiB, output phase
  __shared__ unsigned char skst[PB];    // winning k per position

  const int b     = blockIdx.x & 15;    // batches spread across XCDs
  const int chunk = blockIdx.x >> 4;    // 0..31
  const int bpos0 = chunk * PB;
  const int tid   = threadIdx.x;

  const float* pbr = proto + (size_t)b * K * D;
  for (int i = tid; i < K * D; i += 256) {
    const int k = i >> 8, d = i & 255;
    const float v = pbr[i];
    spd[d][k] = (double)v;
    spf[d][k] = v;
  }
  __syncthreads();

  // ---- dot phase ----
  const int lane = tid & 63;
  const int wv   = tid >> 6;
  const int kh   = lane & 1;            // 0: k=0..8, 1: k=9..17
  const int pair = lane >> 1;           // 0..31
  const int lpos = wv * 128 + pair * 4; // block-local position of this pair
  const float* fin = assp + (size_t)b * D * S + bpos0 + lpos;

  double acc[4][KH];
#pragma unroll
  for (int jp = 0; jp < 4; ++jp)
#pragma unroll
    for (int j = 0; j < KH; ++j) acc[jp][j] = 0.0;

  const int rot = (chunk + 4 * b) & 31;
  float4 fvA[8], fvB[8];

  int dA = rot * 8;                     // group tt=0
#pragma unroll
  for (int jd = 0; jd < 8; ++jd)
    fvA[jd] = *(const float4*)(fin + (size_t)(dA + jd) * S);

  for (int tt = 0; tt < 32; tt += 2) {
    const int dB = ((tt + 1 + rot) & 31) * 8;
#pragma unroll
    for (int jd = 0; jd < 8; ++jd)      // prefetch group tt+1
      fvB[jd] = *(const float4*)(fin + (size_t)(dB + jd) * S);
    COMPUTE_GROUP(fvA, dA);
    const int dA2 = ((tt + 2 + rot) & 31) * 8;
    if (tt + 2 < 32) {
#pragma unroll
      for (int jd = 0; jd < 8; ++jd)    // prefetch group tt+2
        fvA[jd] = *(const float4*)(fin + (size_t)(dA2 + jd) * S);
    }
    COMPUTE_GROUP(fvB, dB);
    dA = dA2;
  }

  // ---- per-position argmin: own half, then cross-pair combine ----
  const double* p2h = p2 + (size_t)b * K + kh * KH;
  int kst[4];
#pragma unroll
  for (int jp = 0; jp < 4; ++jp) {
    double bb = 1e300;
    int bj = 0;
#pragma unroll
    for (int j = 0; j < KH; ++j) {
      const double d2 = p2h[j] - 2.0 * acc[jp][j];
      if (d2 < bb) { bb = d2; bj = j; }    // strict <, ascending j
    }
    const int myk = kh * KH + bj;
    const double ob = __shfl_xor(bb, 1, 64);   // partner's half-best
    const int    ok = __shfl_xor(myk, 1, 64);
    const double bLow  = kh ? ob  : bb;
    const int    kLow  = kh ? ok  : myk;
    const double bHigh = kh ? bb  : ob;
    const int    kHigh = kh ? myk : ok;
    kst[jp] = (bLow <= bHigh) ? kLow : kHigh;  // ties -> lower k = first-min
  }

  if (kh == 0) {
    uchar4 kk;
    kk.x = (unsigned char)kst[0];
    kk.y = (unsigned char)kst[1];
    kk.z = (unsigned char)kst[2];
    kk.w = (unsigned char)kst[3];
    *(uchar4*)&skst[lpos] = kk;
  }
  __syncthreads();

  // ---- output phase: 2 positions/thread, d descending (L3-absorbed) ----
  const int p = 2 * tid;                       // block-local
  const uchar2 kk2 = *(const uchar2*)&skst[p];
  const uchar2 m   = *(const uchar2*)(mask + bpos0 + p);
  const float* fin2 = assp + (size_t)b * D * S + bpos0 + p;
  float*       op   = out  + (size_t)b * D * S + bpos0 + p;
  const int k0 = kk2.x, k1 = kk2.y;

  for (int d0 = D - 8; d0 >= 0; d0 -= 8) {
    float2 fa[8];
#pragma unroll
    for (int jd = 0; jd < 8; ++jd)
      fa[jd] = *(const float2*)(fin2 + (size_t)(d0 + jd) * S);
#pragma unroll
    for (int jd = 0; jd < 8; ++jd) {
      const int d = d0 + jd;
      float2 o;
      o.x = m.x ? spf[d][k0] : fa[jd].x;
      o.y = m.y ? spf[d][k1] : fa[jd].y;
      *(float2*)(op + (size_t)d * S) = o;
    }
  }
}

extern "C" void kernel_launch(void* const* d_in, const int* in_sizes, int n_in,
                              void* d_out, int out_size, void* d_ws, size_t ws_size,
                              hipStream_t stream) {
  const float* assp  = (const float*)d_in[0];
  const float* proto = (const float*)d_in[1];
  const int*   idx   = (const int*)d_in[2];
  float* out = (float*)d_out;

  // ws layout: [mask: S bytes][p2: B*K doubles]
  unsigned char* mask = (unsigned char*)d_ws;
  double*        p2   = (double*)((char*)d_ws + S);

  hipMemsetAsync(mask, 0, S, stream);   // 16 KiB
  prep2_kernel<<<104, 256, 0, stream>>>(proto, idx, mask, p2);
  fused_kernel<<<B * (S / PB), 256, 0, stream>>>(assp, proto, p2, mask, out);
}

// Round 12
// 207.219 us; speedup vs baseline: 2.3242x; 2.3242x over previous
//
#include <hip/hip_runtime.h>

// Problem constants (from reference setup_inputs)
constexpr int B = 16;
constexpr int D = 256;
constexpr int K = 18;
constexpr int KH = 9;            // half-K (lane-pair split)
constexpr int SZ = 128;
constexpr int S = SZ * SZ;       // 16384 positions per plane
constexpr int N = S / 2;         // 8192 sampled positions
constexpr int PB = 512;          // positions per block (argmin)
constexpr int TP = 4;            // planes per staging tile
constexpr int NT = D / TP;       // 64 tiles

// async global->LDS, 16B per lane (dest = uniform base + lane*16)
__device__ __forceinline__ void load_lds16(const float* g, float* l) {
  __builtin_amdgcn_global_load_lds(
      (const __attribute__((address_space(1))) void*)g,
      (__attribute__((address_space(3))) void*)l, 16, 0, 0);
}

// ---------------------------------------------------------------------------
// Prep (identical to passing rounds 5-10): blocks 0..31 scatter mask ones
// (mask pre-zeroed by memset); blocks 32..103 compute p2 = ||proto||^2 fp64.
// ---------------------------------------------------------------------------
__global__ __launch_bounds__(256) void prep2_kernel(
    const float* __restrict__ proto,
    const int* __restrict__ idx,
    unsigned char* __restrict__ mask,
    double* __restrict__ p2) {
  const int blk = blockIdx.x;
  if (blk < 32) {
    mask[idx[blk * 256 + threadIdx.x]] = 1;   // indices are a permutation
  } else {
    const int row  = (blk - 32) * 4 + (threadIdx.x >> 6);  // 0..287 = b*K+k
    const int lane = threadIdx.x & 63;
    const float4 v = *(const float4*)(proto + (size_t)row * D + lane * 4);
    double s = (double)v.x * (double)v.x + (double)v.y * (double)v.y
             + (double)v.z * (double)v.z + (double)v.w * (double)v.w;
#pragma unroll
    for (int off = 1; off < 64; off <<= 1)
      s += __shfl_xor(s, off, 64);
    if (lane == 0) p2[row] = s;
  }
}

// ---------------------------------------------------------------------------
// Argmin. Block = 256 threads (4 waves), (b, 512-pos chunk), grid 512.
// r10's proven numerics (pair K-split, P=4, fp64, d-ascending -> decisions
// bit-identical to rounds 1-10, absmax 0.0) with ONE structural change:
// f comes through a double-buffered LDS tile filled by global_load_lds
// (zero VGPR cost -> no r11-style spill; VGPR ~100 incl. acc 72).
// Schedule = T3 minimum 2-phase: stage(t+1) -> compute(t) -> barrier-drain;
// each tile's loads have a full tile of compute (~600+ cyc) to land,
// fixing the ~2-loads-in-flight latency wall measured in r10 (2.7 TB/s).
// ---------------------------------------------------------------------------
__global__ __launch_bounds__(256, 2) void argmin_kernel(
    const float* __restrict__ assp,
    const float* __restrict__ proto,
    const double* __restrict__ p2,
    signed char* __restrict__ table) {
  __shared__ double spd[D][K];           // 36 KiB: fp64 protos [d][k]
  __shared__ float  fs[2][TP][PB];       // 16 KiB: f tile double-buffer

  const int b     = blockIdx.x & 15;     // batches spread across XCDs
  const int chunk = blockIdx.x >> 4;     // 0..31
  const int bpos0 = chunk * PB;
  const int tid   = threadIdx.x;
  const int lane  = tid & 63;
  const int wv    = tid >> 6;            // wave 0..3
  const int kh    = lane & 1;            // 0: k=0..8, 1: k=9..17
  const int pair  = lane >> 1;           // 0..31
  const int lpos  = wv * 128 + pair * 4; // block-local position of this pair

  const float* pbr = proto + (size_t)b * K * D;
  for (int i = tid; i < K * D; i += 256)
    spd[i & 255][i >> 8] = (double)pbr[i];

  const float* gbase = assp + (size_t)b * D * S + bpos0;

  // prologue: stage tile 0 (wave wv stages plane wv; 2 x 1KB calls)
  {
    const float* src = gbase + (size_t)wv * S + lane * 4;
    load_lds16(src,       &fs[0][wv][0]);
    load_lds16(src + 256, &fs[0][wv][256]);
  }
  __syncthreads();   // drains stage vmcnt + spd lgkm (full-fence semantics)

  double acc[4][KH];
#pragma unroll
  for (int jp = 0; jp < 4; ++jp)
#pragma unroll
    for (int j = 0; j < KH; ++j) acc[jp][j] = 0.0;

  int buf = 0;
  for (int t = 0; t < NT; ++t) {
    if (t + 1 < NT) {                    // stage tile t+1 into other buffer
      const float* src = gbase + (size_t)((t + 1) * TP + wv) * S + lane * 4;
      load_lds16(src,       &fs[buf ^ 1][wv][0]);
      load_lds16(src + 256, &fs[buf ^ 1][wv][256]);
    }
#pragma unroll
    for (int dj = 0; dj < TP; ++dj) {    // compute tile t (loads in flight)
      const int d = t * TP + dj;
      const float4 f4 = *(const float4*)&fs[buf][dj][lpos];
      const double f0 = (double)f4.x, f1 = (double)f4.y;
      const double f2 = (double)f4.z, f3 = (double)f4.w;
      const double* pr = &spd[d][kh * KH];   // 2 unique addrs/wave: broadcast
#pragma unroll
      for (int j = 0; j < KH; ++j) {
        const double pk = pr[j];
        acc[0][j] += f0 * pk;
        acc[1][j] += f1 * pk;
        acc[2][j] += f2 * pk;
        acc[3][j] += f3 * pk;
      }
    }
    __syncthreads();                     // tile t readers done + t+1 staged
    buf ^= 1;
  }

  // ---- per-position argmin: own half, then cross-pair combine (r10) ----
  const double* p2h = p2 + (size_t)b * K + kh * KH;
  int kst[4];
#pragma unroll
  for (int jp = 0; jp < 4; ++jp) {
    double bb = 1e300;
    int bj = 0;
#pragma unroll
    for (int j = 0; j < KH; ++j) {
      const double d2 = p2h[j] - 2.0 * acc[jp][j];
      if (d2 < bb) { bb = d2; bj = j; }      // strict <, ascending j
    }
    const int myk = kh * KH + bj;
    const double ob = __shfl_xor(bb, 1, 64); // partner's half-best
    const int    ok = __shfl_xor(myk, 1, 64);
    const double bLow  = kh ? ob  : bb;
    const int    kLow  = kh ? ok  : myk;
    const double bHigh = kh ? bb  : ob;
    const int    kHigh = kh ? myk : ok;
    kst[jp] = (bLow <= bHigh) ? kLow : kHigh; // ties -> lower k = first-min
  }

  if (kh == 0) {
    uchar4 kk;
    kk.x = (unsigned char)kst[0];
    kk.y = (unsigned char)kst[1];
    kk.z = (unsigned char)kst[2];
    kk.w = (unsigned char)kst[3];
    *(uchar4*)&table[(size_t)b * S + bpos0 + lpos] = kk;
  }
}

// ---------------------------------------------------------------------------
// Scatter (r5-verbatim, proven 7.2 TB/s): one block per (b,d) plane, walked
// d-DESCENDING (L3 tail reuse). Plain stores only (nt stores broke r4).
// ---------------------------------------------------------------------------
__global__ __launch_bounds__(256) void scatter_kernel(
    const float* __restrict__ assp,
    const float* __restrict__ proto,
    const signed char* __restrict__ table,
    const unsigned char* __restrict__ mask,
    float* __restrict__ out) {
  const int d  = 255 - (blockIdx.x >> 4);   // d descending across all b
  const int b  = blockIdx.x & 15;
  const int bd = b * D + d;

  __shared__ float sp[K];
  if (threadIdx.x < K)
    sp[threadIdx.x] = proto[((size_t)b * K + threadIdx.x) * D + d];
  __syncthreads();

  const signed char* tb = table + (size_t)b * S;
  const float4* in4 = (const float4*)(assp + (size_t)bd * S);
  float4* out4 = (float4*)(out + (size_t)bd * S);

#pragma unroll
  for (int it = 0; it < S / 4 / 256; ++it) {   // 16 iterations
    const int i = it * 256 + threadIdx.x;      // float4 index within plane
    char4 t, m;
    *(int*)&t = ((const int*)tb)[i];
    *(int*)&m = ((const int*)mask)[i];
    float4 v = in4[i];
    if (m.x) v.x = sp[(int)t.x];
    if (m.y) v.y = sp[(int)t.y];
    if (m.z) v.z = sp[(int)t.z];
    if (m.w) v.w = sp[(int)t.w];
    out4[i] = v;
  }
}

extern "C" void kernel_launch(void* const* d_in, const int* in_sizes, int n_in,
                              void* d_out, int out_size, void* d_ws, size_t ws_size,
                              hipStream_t stream) {
  const float* assp  = (const float*)d_in[0];
  const float* proto = (const float*)d_in[1];
  const int*   idx   = (const int*)d_in[2];
  float* out = (float*)d_out;

  // ws layout: [table: B*S bytes][mask: S bytes][p2: B*K doubles]
  signed char*   table = (signed char*)d_ws;
  unsigned char* mask  = (unsigned char*)d_ws + (size_t)B * S;
  double*        p2    = (double*)((char*)d_ws + (size_t)B * S + S);

  hipMemsetAsync(mask, 0, S, stream);   // 16 KiB
  prep2_kernel<<<104, 256, 0, stream>>>(proto, idx, mask, p2);
  argmin_kernel<<<B * (S / PB), 256, 0, stream>>>(assp, proto, p2, table);
  scatter_kernel<<<B * D, 256, 0, stream>>>(assp, proto, table, mask, out);
}